// Round 9
// baseline (87.814 us; speedup 1.0000x reference)
//
#include <hip/hip_runtime.h>

// Problem constants (match reference.py)
#define NCLASS 100
#define DDIM   512
#define NROWS  131072

#define CHUNK    4096               // rows per chunk
#define NCHUNK   (NROWS / CHUNK)    // 32
#define NSPLIT   16                 // row-splits per chunk
#define AWAVES   4                  // waves per accum block (256 threads)
#define WSLOTS   (NSPLIT * AWAVES)  // 64 wave-slots per chunk
#define SPAN     (CHUNK / WSLOTS)   // 64 rows nominal per wave-slot
#define ATHREADS 256
#define STHREADS 1024
#define SROWS    (CHUNK / STHREADS) // 4 labels per sort thread

typedef float f32x4 __attribute__((ext_vector_type(4)));

__device__ __forceinline__ float4 ntload(const float4* p) {
    const f32x4 v = __builtin_nontemporal_load((const f32x4*)p);
    return make_float4(v.x, v.y, v.z, v.w);
}

// ---------------------------------------------------------------------------
// Kernel 0: per-chunk counting sort of labels (labels-only). Emits class-
// sorted global row ids, class offsets, counts, and 64 per-chunk wave-slot
// class spans (slot s owns classes whose segment STARTS in [64s, 64(s+1))).
// Each class belongs to exactly one slot -> every partial written exactly once.
// ---------------------------------------------------------------------------
__global__ __launch_bounds__(STHREADS) void icv_sort_kernel(
    const int* __restrict__ labels,
    int* __restrict__ rows_g,   // [NCHUNK][CHUNK] global row ids, class-sorted
    int* __restrict__ off_g,    // [NCHUNK][NCLASS+1]
    int* __restrict__ cnt_p,    // [NCHUNK][NCLASS]
    int* __restrict__ span_g,   // [NCHUNK][WSLOTS][2]
    int* __restrict__ sync_cnt)
{
    __shared__ int s_cnt[NCLASS];
    __shared__ int s_off[NCLASS + 1];
    __shared__ int s_pos[NCLASS];
    __shared__ int s_scan[128];
    __shared__ int s_rows[CHUNK];

    const int tid   = threadIdx.x;
    const int chunk = blockIdx.x;
    const int row0  = chunk * CHUNK;

    if (tid < NCLASS) s_cnt[tid] = 0;
    if (chunk == 0 && tid == 0) *sync_cnt = 0;     // re-init every call
    __syncthreads();

    int labv[SROWS];
    #pragma unroll
    for (int k = 0; k < SROWS; ++k) {
        labv[k] = labels[row0 + k * STHREADS + tid];   // coalesced
        atomicAdd(&s_cnt[labv[k]], 1);
    }
    __syncthreads();

    // exclusive prefix over 100 bins (128-wide Hillis-Steele)
    if (tid < 128) s_scan[tid] = (tid < NCLASS) ? s_cnt[tid] : 0;
    __syncthreads();
    #pragma unroll
    for (int d = 1; d < 128; d <<= 1) {
        int v = 0;
        if (tid < 128) { v = s_scan[tid]; if (tid >= d) v += s_scan[tid - d]; }
        __syncthreads();
        if (tid < 128) s_scan[tid] = v;
        __syncthreads();
    }
    if (tid < NCLASS) { const int e = s_scan[tid] - s_cnt[tid]; s_off[tid] = e; s_pos[tid] = e; }
    if (tid == NCLASS) s_off[NCLASS] = CHUNK;
    __syncthreads();

    #pragma unroll
    for (int k = 0; k < SROWS; ++k) {
        const int p = atomicAdd(&s_pos[labv[k]], 1);
        s_rows[p] = row0 + k * STHREADS + tid;
    }

    // wave-slot class spans: owner(c) = min(s_off[c]/SPAN, WSLOTS-1);
    // owner is non-decreasing in c -> contiguous class ranges, full partition.
    if (tid < WSLOTS) {
        int cf = NCLASS, ce = NCLASS;
        for (int c = 0; c < NCLASS; ++c) {
            int ow = s_off[c] / SPAN; if (ow > WSLOTS - 1) ow = WSLOTS - 1;
            if (ow == tid && cf == NCLASS) cf = c;
            if (ow > tid) { ce = c; break; }
        }
        if (cf > ce) cf = ce;                      // empty slot
        span_g[(chunk * WSLOTS + tid) * 2 + 0] = cf;
        span_g[(chunk * WSLOTS + tid) * 2 + 1] = ce;
    }
    __syncthreads();

    #pragma unroll
    for (int k = 0; k < SROWS; ++k)
        rows_g[chunk * CHUNK + k * STHREADS + tid] = s_rows[k * STHREADS + tid];
    if (tid < NCLASS) {
        off_g[chunk * (NCLASS + 1) + tid] = s_off[tid];
        cnt_p[chunk * NCLASS + tid]       = s_cnt[tid];
    }
    if (tid == NCLASS) off_g[chunk * (NCLASS + 1) + NCLASS] = CHUNK;
}

// ---------------------------------------------------------------------------
// Kernel 1: pure streaming accumulation, FULL-ROW granule. Grid = 32 chunks
// x 16 splits = 512 blocks of 256 threads (2 blocks/CU). Wave-slot ws =
// split*4 + wave streams its snapped class span; each row is one contiguous
// 2 KB nontemporal read (2x float4 per lane), depth-4 ring (8 KB in flight
// per wave), register accumulation, per-class flush = plain coalesced stores.
// ---------------------------------------------------------------------------
__global__ __launch_bounds__(ATHREADS, 2) void icv_accum_kernel(
    const float* __restrict__ feat,     // [NROWS][DDIM]
    const int*   __restrict__ rows_g,
    const int*   __restrict__ off_g,
    const int*   __restrict__ span_g,
    float*       __restrict__ sums_p,   // [NCHUNK][NCLASS][DDIM]
    float*       __restrict__ sq_p)     // [NCHUNK][NCLASS]
{
    __shared__ int s_rows[CHUNK];       // 16 KB
    __shared__ int s_off[NCLASS + 1];

    const int tid   = threadIdx.x;
    const int wave  = tid >> 6;
    const int lane  = tid & 63;
    const int b     = blockIdx.x;
    const int chunk = b >> 4;
    const int split = b & 15;

    #pragma unroll
    for (int k = 0; k < CHUNK / ATHREADS; ++k)
        s_rows[k * ATHREADS + tid] = rows_g[chunk * CHUNK + k * ATHREADS + tid];
    if (tid < NCLASS + 1) s_off[tid] = off_g[chunk * (NCLASS + 1) + tid];
    __syncthreads();

    const int ws = split * AWAVES + wave;
    const int cf = span_g[(chunk * WSLOTS + ws) * 2 + 0];
    const int ce = span_g[(chunk * WSLOTS + ws) * 2 + 1];
    const int i0 = s_off[cf];
    const int i1 = s_off[ce];

    const float4* f4 = (const float4*)feat;        // row stride DDIM/4 = 128

    int    c    = cf;
    int    cend = (c < ce) ? s_off[c + 1] : (CHUNK + 1);
    float4 accA = make_float4(0.f, 0.f, 0.f, 0.f);
    float4 accB = make_float4(0.f, 0.f, 0.f, 0.f);
    float  sq   = 0.f;

#define LOADA(idx) ntload(&f4[(size_t)s_rows[(idx)] * (DDIM / 4) + lane])
#define LOADB(idx) ntload(&f4[(size_t)s_rows[(idx)] * (DDIM / 4) + 64 + lane])

#define FLUSH() do {                                                          \
        float s_ = sq;                                                        \
        s_ += __shfl_xor(s_, 32, 64); s_ += __shfl_xor(s_, 16, 64);           \
        s_ += __shfl_xor(s_,  8, 64); s_ += __shfl_xor(s_,  4, 64);           \
        s_ += __shfl_xor(s_,  2, 64); s_ += __shfl_xor(s_,  1, 64);           \
        float4* dst_ = (float4*)(sums_p                                       \
            + ((size_t)(chunk * NCLASS + c) * DDIM));                         \
        dst_[lane]      = accA;                                               \
        dst_[64 + lane] = accB;                                               \
        if (lane == 0) sq_p[chunk * NCLASS + c] = s_;                         \
        accA = make_float4(0.f, 0.f, 0.f, 0.f);                               \
        accB = make_float4(0.f, 0.f, 0.f, 0.f);                               \
        sq = 0.f;                                                             \
        ++c;                                                                  \
        cend = (c < ce) ? s_off[c + 1] : (CHUNK + 1);                         \
    } while (0)

#define STEP(K, RA, RB) {                                                     \
        const int i_ = ib + (K);                                              \
        if (i_ < i1) {                                                        \
            while (i_ >= cend) FLUSH();                                       \
            const float4 a_ = RA;                                             \
            const float4 b_ = RB;                                             \
            const int ip_ = i_ + 4;                                           \
            if (ip_ < i1) { RA = LOADA(ip_); RB = LOADB(ip_); }               \
            accA.x += a_.x; accA.y += a_.y; accA.z += a_.z; accA.w += a_.w;   \
            accB.x += b_.x; accB.y += b_.y; accB.z += b_.z; accB.w += b_.w;   \
            sq = fmaf(a_.x, a_.x, fmaf(a_.y, a_.y,                            \
                 fmaf(a_.z, a_.z, fmaf(a_.w, a_.w, sq))));                    \
            sq = fmaf(b_.x, b_.x, fmaf(b_.y, b_.y,                            \
                 fmaf(b_.z, b_.z, fmaf(b_.w, b_.w, sq))));                    \
        }                                                                     \
    }

    float4 r0a = make_float4(0.f, 0.f, 0.f, 0.f), r0b = r0a;
    float4 r1a = r0a, r1b = r0a, r2a = r0a, r2b = r0a, r3a = r0a, r3b = r0a;
    if (i0 + 0 < i1) { r0a = LOADA(i0 + 0); r0b = LOADB(i0 + 0); }
    if (i0 + 1 < i1) { r1a = LOADA(i0 + 1); r1b = LOADB(i0 + 1); }
    if (i0 + 2 < i1) { r2a = LOADA(i0 + 2); r2b = LOADB(i0 + 2); }
    if (i0 + 3 < i1) { r3a = LOADA(i0 + 3); r3b = LOADB(i0 + 3); }

    for (int ib = i0; ib < i1; ib += 4) {
        STEP(0, r0a, r0b)
        STEP(1, r1a, r1b)
        STEP(2, r2a, r2b)
        STEP(3, r3a, r3b)
    }
    while (c < ce) FLUSH();                        // tail incl. empty classes
#undef STEP
#undef FLUSH
#undef LOADA
#undef LOADB
}

// ---------------------------------------------------------------------------
// Kernel 2: per-class reduction of partials -> trace/valid, fused with the
// final valid-mean via last-block pattern (device-scope fence + atomic).
// ---------------------------------------------------------------------------
__global__ __launch_bounds__(512) void icv_reduce_kernel(
    const float* __restrict__ sums_p,   // [NCHUNK][NCLASS][DDIM]
    const float* __restrict__ sq_p,     // [NCHUNK][NCLASS]
    const int*   __restrict__ cnt_p,    // [NCHUNK][NCLASS]
    float*       __restrict__ cls_out,  // [NCLASS][2]
    int*         __restrict__ sync_cnt,
    float*       __restrict__ out)
{
    __shared__ float red[3][8];
    __shared__ float fin[2][8];
    __shared__ int   s_last;

    const int c    = blockIdx.x;
    const int t    = threadIdx.x;
    const int wave = t >> 6;
    const int lane = t & 63;

    // thread t owns column t of class c, summed over chunks
    float s = 0.f;
    const float* p = sums_p + (size_t)c * DDIM + t;
    #pragma unroll 8
    for (int ch = 0; ch < NCHUNK; ++ch)
        s += p[(size_t)ch * (NCLASS * DDIM)];

    float v1 = s * s;                                          // -> ||sum_c||^2
    float v2 = (t < NCHUNK) ? sq_p[t * NCLASS + c] : 0.f;
    float v3 = (t < NCHUNK) ? (float)cnt_p[t * NCLASS + c] : 0.f;
    #pragma unroll
    for (int off = 32; off > 0; off >>= 1) {
        v1 += __shfl_xor(v1, off, 64);
        v2 += __shfl_xor(v2, off, 64);
        v3 += __shfl_xor(v3, off, 64);
    }
    if (lane == 0) { red[0][wave] = v1; red[1][wave] = v2; red[2][wave] = v3; }
    __syncthreads();

    if (t == 0) {
        float n2 = 0.f, sq = 0.f, n = 0.f;
        #pragma unroll
        for (int w = 0; w < 8; ++w) { n2 += red[0][w]; sq += red[1][w]; n += red[2][w]; }
        const float safe  = fmaxf(n, 1.f);
        const float ssd   = sq - n2 / safe;        // sq - n*||sums/n||^2
        const float trace = ssd / fmaxf(n - 1.f, 1.f);
        const bool  valid = (n >= 2.f);
        cls_out[c * 2 + 0] = valid ? trace : 0.f;
        cls_out[c * 2 + 1] = valid ? 1.f : 0.f;
        __threadfence();                           // release class result
        const int done = atomicAdd(sync_cnt, 1);   // device-scope
        s_last = (done == NCLASS - 1) ? 1 : 0;
    }
    __syncthreads();

    if (s_last) {                                  // uniform across block
        __threadfence();                           // acquire others' results
        float tv = 0.f, vv = 0.f;
        if (t < NCLASS) {
            const volatile float* cv = (const volatile float*)cls_out;
            tv = cv[t * 2 + 0];
            vv = cv[t * 2 + 1];
        }
        #pragma unroll
        for (int off = 32; off > 0; off >>= 1) {
            tv += __shfl_xor(tv, off, 64);
            vv += __shfl_xor(vv, off, 64);
        }
        if (lane == 0) { fin[0][wave] = tv; fin[1][wave] = vv; }
        __syncthreads();
        if (t == 0) {
            float tot = 0.f, vc = 0.f;
            #pragma unroll
            for (int w = 0; w < 8; ++w) { tot += fin[0][w]; vc += fin[1][w]; }
            out[0] = (vc > 0.f) ? (tot / fmaxf(vc, 1.f)) : 0.f;
        }
    }
}

extern "C" void kernel_launch(void* const* d_in, const int* in_sizes, int n_in,
                              void* d_out, int out_size, void* d_ws, size_t ws_size,
                              hipStream_t stream) {
    const float* feat   = (const float*)d_in[0];
    const int*   labels = (const int*)d_in[1];
    float* out = (float*)d_out;

    // Workspace (all slots written unconditionally every call -> no memset):
    float* sums_p  = (float*)d_ws;                              // 6.55 MB
    float* sq_p    = sums_p + (size_t)NCHUNK * NCLASS * DDIM;   // 13 KB
    int*   cnt_p   = (int*)(sq_p + NCHUNK * NCLASS);            // 13 KB
    int*   rows_g  = cnt_p + NCHUNK * NCLASS;                   // 524 KB
    int*   off_g   = rows_g + NCHUNK * CHUNK;                   // 13 KB
    int*   span_g  = off_g + NCHUNK * (NCLASS + 1);             // 16 KB
    float* cls_out = (float*)(span_g + NCHUNK * WSLOTS * 2);
    int*   sync_cnt= (int*)(cls_out + NCLASS * 2);

    icv_sort_kernel<<<dim3(NCHUNK), STHREADS, 0, stream>>>(
        labels, rows_g, off_g, cnt_p, span_g, sync_cnt);
    icv_accum_kernel<<<dim3(NCHUNK * NSPLIT), ATHREADS, 0, stream>>>(
        feat, rows_g, off_g, span_g, sums_p, sq_p);
    icv_reduce_kernel<<<dim3(NCLASS), 512, 0, stream>>>(
        sums_p, sq_p, cnt_p, cls_out, sync_cnt, out);
}